// Round 15
// baseline (41.643 us; speedup 1.0000x reference)
//
#include <hip/hip_runtime.h>
#include <hip/hip_fp16.h>

typedef __attribute__((ext_vector_type(4))) float f32x4;
typedef __attribute__((ext_vector_type(8))) _Float16 f16x8;
typedef __attribute__((ext_vector_type(2))) _Float16 f16x2;
typedef __attribute__((ext_vector_type(2))) __fp16 fp16x2_raw;

union F16X8 { f16x2 p[4]; f16x8 w; };

static __device__ __forceinline__ f16x2 pkrtz(float a, float b) {
    fp16x2_raw r = __builtin_amdgcn_cvt_pkrtz(a, b);  // v_cvt_pkrtz_f16_f32
    return __builtin_bit_cast(f16x2, r);
}
static __device__ __forceinline__ f16x2 splat16(unsigned short s) {
    unsigned v = (unsigned)s | ((unsigned)s << 16);
    return __builtin_bit_cast(f16x2, v);
}

#define QS 72   // qs16 row stride (shorts): 144B rows, 16B-aligned

// Load B-fragment for slice dd: 16 coalesced dwords, 4x64B segments per inst.
// sched_barrier(0) pins the loads at their program point (anti-sink).
#define LOADB(BUF, dd) do {                                           \
    const float* _p = Sb + (size_t)(dd) * 4096;                       \
    _Pragma("unroll") for (int _K = 0; _K < 2; ++_K)                  \
    _Pragma("unroll") for (int _j = 0; _j < 8; ++_j)                  \
        b##BUF[_K][_j] = _p[_K * 2048 + _j * 64];                     \
    __builtin_amdgcn_sched_barrier(0);                                \
} while (0)

// Compute slice dd: convert B to f16, A = s_d (f16 LDS broadcast) * u_e, 8 MFMA.
#define COMPUTE(BUF, dd) do {                                         \
    f16x8 _bb[2];                                                     \
    _Pragma("unroll") for (int _K = 0; _K < 2; ++_K) {                \
        F16X8 _bu;                                                    \
        _Pragma("unroll") for (int _h = 0; _h < 4; ++_h)              \
            _bu.p[_h] = pkrtz(b##BUF[_K][2*_h], b##BUF[_K][2*_h+1]);  \
        _bb[_K] = _bu.w;                                              \
    }                                                                 \
    _Pragma("unroll") for (int _M = 0; _M < 4; ++_M) {                \
        f16x2 _sh = splat16(qs16[(_M * 16 + ra) * QS + (dd)]);        \
        _Pragma("unroll") for (int _K = 0; _K < 2; ++_K) {            \
            F16X8 _au;                                                \
            _Pragma("unroll") for (int _h = 0; _h < 4; ++_h)          \
                _au.p[_h] = _sh * u[_M][_K][_h];                      \
            acc[_M] = __builtin_amdgcn_mfma_f32_16x16x32_f16(_au.w, _bb[_K], acc[_M], 0, 0, 0); \
        }                                                             \
    }                                                                 \
} while (0)

// waves_per_eu(2,2): min AND MAX. Caps occupancy at 2 waves/EU so the scheduler
// stops minimizing VGPRs toward 8-wave occupancy (the R2..R14 spill/de-pipeline
// pathology: VGPR_Count 56-96 vs >=112 required by the named buffers).
__global__ __attribute__((amdgpu_flat_work_group_size(256, 256)))
__attribute__((amdgpu_waves_per_eu(2, 2)))
void quad_form_kernel(
    const float* __restrict__ q, const float* __restrict__ kv, float* __restrict__ out)
{
    __shared__ unsigned short qs16[64 * QS];   // 9216 B: f16(q*0.125), WG's 64 rows

    const int tid = threadIdx.x;

    // c-quarter split: WG = 64 c-rows x all 64 f. Wave w owns f-slab w*16 (disjoint
    // 256KB S stream). 4 c-sibling WGs of a chunk on one XCD -> L2 absorbs re-reads.
    const int wg = blockIdx.x;             // 0..511
    const int xcd = wg & 7, p = wg >> 3;   // p 0..63
    const int chunk = xcd * 16 + (p >> 2); // 0..127
    const int cq = p & 3;

    const int lane = tid & 63;
    const int w = tid >> 6;                // wave -> f-slab w*16
    const int ra = lane & 15, kg = lane >> 4;

    const float* qch = q  + (size_t)chunk * 16384 + cq * 4096;   // 64 rows x 64
    const float* Sch = kv + (size_t)chunk * 262144;
    float*       och = out + (size_t)chunk * 16384 + cq * 4096;

    // ---- stage q quarter (64x64) -> LDS f16, scaled by 0.125 (exact) ----
#pragma unroll
    for (int i = 0; i < 4; ++i) {
        int idx4 = i * 256 + tid;            // f32x4 index 0..1023
        int row = idx4 >> 4, col4 = idx4 & 15;
        f32x4 v = *(const f32x4*)(qch + idx4 * 4);
        v *= 0.125f;
        f16x2 h0 = pkrtz(v[0], v[1]);
        f16x2 h1 = pkrtz(v[2], v[3]);
        unsigned pair[2] = { __builtin_bit_cast(unsigned, h0),
                             __builtin_bit_cast(unsigned, h1) };
        *(unsigned long long*)&qs16[row * QS + col4 * 4] =
            *(unsigned long long*)pair;      // ds_write_b64
    }
    __syncthreads();   // only barrier; qs16 read-only afterwards

    // per-lane base: wave-private f-slab
    const float* Sb = Sch + kg * 512 + w * 16 + ra;   // + d*4096 + K*2048 + j*64

    // ---- hoisted A e-fragments u[Mt][Ks][h] (f16, pre-scaled); same for all waves ----
    f16x2 u[4][2][4];
#pragma unroll
    for (int Mt = 0; Mt < 4; ++Mt)
#pragma unroll
        for (int Ks = 0; Ks < 2; ++Ks) {
            F16X8 t;
            t.w = *(const f16x8*)&qs16[(Mt * 16 + ra) * QS + Ks * 32 + kg * 8];
#pragma unroll
            for (int h = 0; h < 4; ++h) u[Mt][Ks][h] = t.p[h];
        }

    f32x4 acc[4] = {};
    float bA[2][8], bB[2][8], bC[2][8], bD[2][8];  // 4-deep rotation, 64 VGPRs

    LOADB(A, 0); LOADB(B, 1); LOADB(C, 2); LOADB(D, 3);

#pragma unroll 1
    for (int it = 0; it < 16; ++it) {      // 16 iters x 4 slices = 64
        const int d = it * 4;
        COMPUTE(A, d);     if (d + 4 < 64) LOADB(A, d + 4);
        COMPUTE(B, d + 1); if (d + 5 < 64) LOADB(B, d + 5);
        COMPUTE(C, d + 2); if (d + 6 < 64) LOADB(C, d + 6);
        COMPUTE(D, d + 3); if (d + 7 < 64) LOADB(D, d + 7);
    }

    // ---- epilogue: out = 0.5 * acc ----
#pragma unroll
    for (int Mt = 0; Mt < 4; ++Mt)
#pragma unroll
        for (int j = 0; j < 4; ++j)
            och[(Mt * 16 + kg * 4 + j) * 64 + w * 16 + ra] = 0.5f * acc[Mt][j];
}

extern "C" void kernel_launch(void* const* d_in, const int* in_sizes, int n_in,
                              void* d_out, int out_size, void* d_ws, size_t ws_size,
                              hipStream_t stream) {
    const float* q  = (const float*)d_in[0];
    const float* kv = (const float*)d_in[1];
    float* out = (float*)d_out;
    hipLaunchKernelGGL(quad_form_kernel, dim3(512), dim3(256), 0, stream, q, kv, out);
}

// Round 16
// 38.510 us; speedup vs baseline: 1.0814x; 1.0814x over previous
//
#include <hip/hip_runtime.h>
#include <hip/hip_fp16.h>

typedef __attribute__((ext_vector_type(4))) float f32x4;
typedef __attribute__((ext_vector_type(8))) _Float16 f16x8;
typedef __attribute__((ext_vector_type(2))) _Float16 f16x2;
typedef __attribute__((ext_vector_type(2))) __fp16 fp16x2_raw;

union F16X8 { f16x2 p[4]; f16x8 w; };

static __device__ __forceinline__ f16x2 pkrtz(float a, float b) {
    fp16x2_raw r = __builtin_amdgcn_cvt_pkrtz(a, b);  // v_cvt_pkrtz_f16_f32
    return __builtin_bit_cast(f16x2, r);
}

#define QS 68   // LDS row stride (floats): 272B rows; s-reads 2-way (free)

// Load B-fragment for slice dd: 16 coalesced dwords; the WG's 4 waves share the
// same f-slab so 3 of 4 hit L1.
#define LOADB(BUF, dd) do {                                           \
    const float* _p = Sb + (size_t)(dd) * 4096;                       \
    _Pragma("unroll") for (int _K = 0; _K < 2; ++_K)                  \
    _Pragma("unroll") for (int _j = 0; _j < 8; ++_j)                  \
        b##BUF[_K][_j] = _p[_K * 2048 + _j * 64];                     \
} while (0)

// Compute slice dd: convert B to f16, A = s_d (LDS, pre-scaled) * u_e, 8 MFMA.
#define COMPUTE(BUF, dd) do {                                         \
    f16x8 _bb[2];                                                     \
    _Pragma("unroll") for (int _K = 0; _K < 2; ++_K) {                \
        F16X8 _bu;                                                    \
        _Pragma("unroll") for (int _h = 0; _h < 4; ++_h)              \
            _bu.p[_h] = pkrtz(b##BUF[_K][2*_h], b##BUF[_K][2*_h+1]);  \
        _bb[_K] = _bu.w;                                              \
    }                                                                 \
    _Pragma("unroll") for (int _M = 0; _M < 4; ++_M) {                \
        float _sf = qsbase[_M * (16 * QS) + (dd)];                    \
        f16x2 _sh = pkrtz(_sf, _sf);                                  \
        _Pragma("unroll") for (int _K = 0; _K < 2; ++_K) {            \
            F16X8 _au;                                                \
            _Pragma("unroll") for (int _h = 0; _h < 4; ++_h)          \
                _au.p[_h] = _sh * u[_M][_K][_h];                      \
            acc[_M] = __builtin_amdgcn_mfma_f32_16x16x32_f16(_au.w, _bb[_K], acc[_M], 0, 0, 0); \
        }                                                             \
    }                                                                 \
} while (0)

__global__ __launch_bounds__(256, 2) void quad_form_kernel(
    const float* __restrict__ q, const float* __restrict__ kv, float* __restrict__ out)
{
    __shared__ float qs[256 * QS];   // 69632 B: q chunk * 0.125; 2 WGs/CU

    const int tid = threadIdx.x;

    // f-split: 4 WGs per chunk, each owns 16 f-cols and ALL 256 rows -> S read 1x.
    const int wg = blockIdx.x;             // 0..511
    const int xcd = wg & 7, p = wg >> 3;   // p 0..63
    const int chunk = xcd * 16 + (p >> 2); // 0..127
    const int f0 = (p & 3) * 16;

    const int lane = tid & 63;
    const int w = tid >> 6;                // wave = row-quarter (64 rows)
    const int ra = lane & 15, kg = lane >> 4;

    const float* qch = q  + (size_t)chunk * 16384;
    const float* Sch = kv + (size_t)chunk * 262144;
    float*       och = out + (size_t)chunk * 16384;

    // ---- stage q chunk (256x64) -> LDS, scaled by 0.125 (exact) ----
#pragma unroll
    for (int i = 0; i < 16; ++i) {
        int idx4 = i * 256 + tid;
        int row = idx4 >> 4, col = (idx4 & 15) << 2;
        f32x4 v = *(const f32x4*)(qch + idx4 * 4);
        v *= 0.125f;
        *(f32x4*)&qs[row * QS + col] = v;
    }
    __syncthreads();   // only barrier; qs is read-only afterwards

    // per-lane bases
    const float* Sb = Sch + kg * 512 + f0 + ra;        // + d*4096 + K*2048 + j*64
    const float* qsbase = &qs[(w * 64 + ra) * QS];     // + Mt*16*QS + d  (s broadcast)

    // ---- hoisted A e-fragments u[Mt][Ks][h] (f16, pre-scaled by 1/8) ----
    f16x2 u[4][2][4];
#pragma unroll
    for (int Mt = 0; Mt < 4; ++Mt)
#pragma unroll
        for (int Ks = 0; Ks < 2; ++Ks) {
            const float* qr = qsbase + Mt * (16 * QS) + Ks * 32 + kg * 8;
            f32x4 g0 = *(const f32x4*)qr;
            f32x4 g1 = *(const f32x4*)(qr + 4);
            u[Mt][Ks][0] = pkrtz(g0[0], g0[1]);
            u[Mt][Ks][1] = pkrtz(g0[2], g0[3]);
            u[Mt][Ks][2] = pkrtz(g1[0], g1[1]);
            u[Mt][Ks][3] = pkrtz(g1[2], g1[3]);
        }

    f32x4 acc[4] = {};
    float bA[2][8], bB[2][8], bC[2][8];   // 3-deep rotation: 2-slice consume window

    LOADB(A, 0); LOADB(B, 1); LOADB(C, 2);

    int i = 0;
#pragma unroll 1
    for (int it = 0; it < 21; ++it) {      // slices 0..62
        COMPUTE(A, i); if (i + 3 < 64) LOADB(A, i + 3); ++i;
        COMPUTE(B, i); if (i + 3 < 64) LOADB(B, i + 3); ++i;
        COMPUTE(C, i); if (i + 3 < 64) LOADB(C, i + 3); ++i;
    }
    COMPUTE(A, 63);                        // 63 % 3 == 0 -> buffer A

    // ---- epilogue: out = 0.5 * acc ----
#pragma unroll
    for (int Mt = 0; Mt < 4; ++Mt)
#pragma unroll
        for (int j = 0; j < 4; ++j)
            och[(w * 64 + Mt * 16 + kg * 4 + j) * 64 + f0 + ra] = 0.5f * acc[Mt][j];
}

extern "C" void kernel_launch(void* const* d_in, const int* in_sizes, int n_in,
                              void* d_out, int out_size, void* d_ws, size_t ws_size,
                              hipStream_t stream) {
    const float* q  = (const float*)d_in[0];
    const float* kv = (const float*)d_in[1];
    float* out = (float*)d_out;
    hipLaunchKernelGGL(quad_form_kernel, dim3(512), dim3(256), 0, stream, q, kv, out);
}